// Round 3
// baseline (1157.547 us; speedup 1.0000x reference)
//
#include <hip/hip_runtime.h>
#include <hip/hip_bf16.h>
#include <cstdint>

// ---------------------------------------------------------------------------
// SANA MS-AdaLN block on MI355X.
// R1: LN stats via per-block partials (atomic serialization fix).
// R2: 128x256 GEMM tile (gemm256) for the 3 big GEMMs — raises FLOP/LDS-byte
//     (MFMA 620 cyc vs LDS 565 cyc per K-step, was 310 vs 380) and halves
//     barrier drains per FLOP. proj/MLP-proj stay on 128x128 (small grids).
// ---------------------------------------------------------------------------

typedef __bf16 bf16;
typedef bf16 bf16x8 __attribute__((ext_vector_type(8)));
typedef bf16 bf16x4 __attribute__((ext_vector_type(4)));
typedef float f32x4 __attribute__((ext_vector_type(4)));

typedef const __attribute__((address_space(1))) void gas_void;
typedef __attribute__((address_space(3))) void las_void;

__device__ __forceinline__ void gload16(const bf16* g, bf16* l) {
    __builtin_amdgcn_global_load_lds((gas_void*)g, (las_void*)l, 16, 0, 0);
}

// ---- problem constants ----
#define BB 4
#define CC 288
#define HW 4096          // 64*64
#define C6 1728
#define DD 1152
#define SEQ 1026
#define RTOT 4104        // 4*1026
#define NTOK 1024
#define HF 4608
#define HF2 9216
#define NPB 1179648      // elements per batch sample (288*4096)

// ---- workspace layout (bytes) ----
static constexpr size_t OFF_SUMS = 0;                                   // 16 floats
static constexpr size_t OFF_SS   = 256;                                 // bf16 [1728][16384]
static constexpr size_t SS_BYTES = (size_t)C6 * 16384 * 2;              // 56,623,104
static constexpr size_t OFF_R2   = OFF_SS + SS_BYTES;
// phase A
static constexpr size_t OFF_PART1= OFF_R2;                              // f32 [1152][2] (dead before prep_cond)
static constexpr size_t OFF_A1   = OFF_R2;                              // bf16 [16384][1728]
// phase B (A1 dead after GEMM1)
static constexpr size_t OFF_T    = OFF_R2;                              // bf16 [4104][1152]
static constexpr size_t OFF_QKV  = OFF_T   + (size_t)RTOT*DD*2;         // bf16 [3456][4104]
static constexpr size_t OFF_PART2= OFF_QKV;                             // f32 [18432][2] (QKV dead at add_attn)
static constexpr size_t OFF_VK   = OFF_QKV + (size_t)3456*RTOT*2;       // f32  [144][1056]
static constexpr size_t OFF_ATT  = OFF_VK  + (size_t)144*1056*4;        // bf16 [4104][1152]
static constexpr size_t OFF_APROJ= OFF_ATT + (size_t)RTOT*DD*2;         // bf16 [1152][4104]
// phase C (phase B dead after add_attn)
static constexpr size_t OFF_T2   = OFF_R2;                              // bf16 [4096][1152]
static constexpr size_t OFF_Y    = OFF_T2  + (size_t)4096*DD*2;         // bf16 [4096][9216]
static constexpr size_t OFF_G    = OFF_Y   + (size_t)4096*HF2*2;        // bf16 [4096][4608]
static constexpr size_t OFF_M    = OFF_G   + (size_t)4096*HF*2;         // bf16 [1152][4096]
// converted weights (persistent)
static constexpr size_t OFF_W    = OFF_R2  + 132120576;                 // end of phase C
static constexpr size_t OFF_WSS  = OFF_W;
static constexpr size_t OFF_WQKV = OFF_WSS  + (size_t)C6*C6*2;
static constexpr size_t OFF_WPROJ= OFF_WQKV + (size_t)3456*DD*2;
static constexpr size_t OFF_WINV = OFF_WPROJ+ (size_t)DD*DD*2;
static constexpr size_t OFF_WPW  = OFF_WINV + (size_t)HF2*DD*2;

// ---------------------------------------------------------------------------
// fp32 -> bf16 weight conversion
__global__ __launch_bounds__(256) void cvt_bf16(const float* __restrict__ s,
                                                bf16* __restrict__ d, int n4) {
    int i = blockIdx.x * 256 + threadIdx.x;
    if (i < n4) {
        float4 v = ((const float4*)s)[i];
        bf16x4 o = {(bf16)v.x, (bf16)v.y, (bf16)v.z, (bf16)v.w};
        ((bf16x4*)d)[i] = o;
    }
}

// ---------------------------------------------------------------------------
// block reduce (sum, sumsq); thread 0 stores 2 floats (no atomics)
__device__ __forceinline__ void block_reduce2_store(float s1, float s2, float* dst) {
    #pragma unroll
    for (int o = 32; o > 0; o >>= 1) { s1 += __shfl_down(s1, o); s2 += __shfl_down(s2, o); }
    __shared__ float r1[4], r2[4];
    int wave = threadIdx.x >> 6, lane = threadIdx.x & 63;
    if (lane == 0) { r1[wave] = s1; r2[wave] = s2; }
    __syncthreads();
    if (threadIdx.x == 0) {
        dst[0] = r1[0] + r1[1] + r1[2] + r1[3];
        dst[1] = r2[0] + r2[1] + r2[2] + r2[3];
    }
}

// LN1 stats over x: grid 4*288 blocks, 4096 elems/block -> partials
__global__ __launch_bounds__(256) void ln_stats(const float* __restrict__ x, float* __restrict__ part) {
    const float* base = x + (size_t)blockIdx.x * 4096;
    float s1 = 0.f, s2 = 0.f;
    #pragma unroll
    for (int it = 0; it < 4; it++) {
        float4 v = ((const float4*)base)[it * 256 + threadIdx.x];
        s1 += v.x + v.y + v.z + v.w;
        s2 += v.x * v.x + v.y * v.y + v.z * v.z + v.w * v.w;
    }
    block_reduce2_store(s1, s2, part + (size_t)blockIdx.x * 2);
}

// collapse per-block partials -> sums[out_off + b*2 .. +1]. grid = 4 (one per batch)
__global__ __launch_bounds__(256) void reduce_part(const float* __restrict__ part, float* __restrict__ sums,
                                                   int nper, int out_off) {
    int b = blockIdx.x;
    float s1 = 0.f, s2 = 0.f;
    for (int i = threadIdx.x; i < nper; i += 256) {
        s1 += part[(size_t)(b * nper + i) * 2];
        s2 += part[(size_t)(b * nper + i) * 2 + 1];
    }
    block_reduce2_store(s1, s2, sums + out_off + b * 2);
}

// ---------------------------------------------------------------------------
// silu(cond) transpose: (b, k, hw) f32 -> A1[(b,hw)][k] bf16. grid (64,27,4)
__global__ __launch_bounds__(256) void prep_cond(const float* __restrict__ cond, bf16* __restrict__ A1) {
    __shared__ float tile[64][65];
    int b = blockIdx.z, k0 = blockIdx.y * 64, h0 = blockIdx.x * 64;
    int col = threadIdx.x & 63, r4 = threadIdx.x >> 6;
    const float* src = cond + ((size_t)b * C6 + k0) * HW + h0;
    #pragma unroll
    for (int p = 0; p < 16; p++) {
        int kk = r4 + p * 4;
        float v = src[(size_t)kk * HW + col];
        tile[col][kk] = v / (1.f + __expf(-v));
    }
    __syncthreads();
    bf16* dst = A1 + ((size_t)(b * HW + h0)) * C6 + k0;
    #pragma unroll
    for (int p = 0; p < 16; p++) {
        int rr = r4 + p * 4;
        dst[(size_t)rr * C6 + col] = (bf16)tile[rr][col];
    }
}

// ---------------------------------------------------------------------------
// gemm_bt: C[m][n] = sum_k A[m][k]*B[n][k]  (both operands k-contiguous bf16)
// EP: 0=none, 1=relu if m<reluLimit, 2=silu.  BIAS: 0=none, 1=per-m, 2=per-n.
template <int EP, int BIAS>
__global__ __launch_bounds__(256) void gemm_bt(const bf16* __restrict__ A, const bf16* __restrict__ B,
                                               const float* __restrict__ bias, bf16* __restrict__ C,
                                               int M, int N, int K, int reluLimit) {
    __shared__ __align__(16) bf16 As[128 * 32];
    __shared__ __align__(16) bf16 Bs[128 * 32];
    const int tid = threadIdx.x, wave = tid >> 6, lane = tid & 63;
    const int m0 = blockIdx.y * 128, n0 = blockIdx.x * 128;

    const int c0 = wave * 128 + lane;
    const int c1 = c0 + 64;
    const int ka = (c0 & 3) * 8, kb = (c1 & 3) * 8;
    int ra0 = min(m0 + (c0 >> 2), M - 1), ra1 = min(m0 + (c1 >> 2), M - 1);
    int rb0 = min(n0 + (c0 >> 2), N - 1), rb1 = min(n0 + (c1 >> 2), N - 1);
    const bf16* gA0 = A + (size_t)ra0 * K + ka;
    const bf16* gA1 = A + (size_t)ra1 * K + kb;
    const bf16* gB0 = B + (size_t)rb0 * K + ka;
    const bf16* gB1 = B + (size_t)rb1 * K + kb;
    bf16* lA0 = As + wave * 1024;
    bf16* lA1 = As + wave * 1024 + 512;
    bf16* lB0 = Bs + wave * 1024;
    bf16* lB1 = Bs + wave * 1024 + 512;

    const int wm = (wave >> 1) * 64, wn = (wave & 1) * 64;
    const bf16* fa = As + (wm + (lane & 15)) * 32 + (lane >> 4) * 8;
    const bf16* fb = Bs + (wn + (lane & 15)) * 32 + (lane >> 4) * 8;

    f32x4 acc[4][4];
    #pragma unroll
    for (int i = 0; i < 4; i++)
        #pragma unroll
        for (int j = 0; j < 4; j++) acc[i][j] = (f32x4){0.f, 0.f, 0.f, 0.f};

    for (int kt = 0; kt < K; kt += 32) {
        __syncthreads();
        gload16(gA0, lA0); gload16(gA1, lA1);
        gload16(gB0, lB0); gload16(gB1, lB1);
        gA0 += 32; gA1 += 32; gB0 += 32; gB1 += 32;
        __syncthreads();
        bf16x8 af[4], bv[4];
        #pragma unroll
        for (int i = 0; i < 4; i++) af[i] = *(const bf16x8*)(fa + i * 16 * 32);
        #pragma unroll
        for (int j = 0; j < 4; j++) bv[j] = *(const bf16x8*)(fb + j * 16 * 32);
        #pragma unroll
        for (int i = 0; i < 4; i++)
            #pragma unroll
            for (int j = 0; j < 4; j++)
                acc[i][j] = __builtin_amdgcn_mfma_f32_16x16x32_bf16(af[i], bv[j], acc[i][j], 0, 0, 0);
    }

    const int mq = (lane >> 4) * 4, nl = lane & 15;
    #pragma unroll
    for (int i = 0; i < 4; i++) {
        #pragma unroll
        for (int j = 0; j < 4; j++) {
            int n = n0 + wn + j * 16 + nl;
            if (n < N) {
                #pragma unroll
                for (int r = 0; r < 4; r++) {
                    int m = m0 + wm + i * 16 + mq + r;
                    if (m < M) {
                        float v = acc[i][j][r];
                        if (BIAS == 1) v += bias[m];
                        else if (BIAS == 2) v += bias[n];
                        if (EP == 1) { if (m < reluLimit) v = fmaxf(v, 0.f); }
                        else if (EP == 2) { v = v / (1.f + __expf(-v)); }
                        C[(size_t)m * N + n] = (bf16)v;
                    }
                }
            }
        }
    }
}

// ---------------------------------------------------------------------------
// gemm256: 128(m) x 256(n) block tile, 4 waves each 64m x 128n (4x8 frags).
// Same operand convention as gemm_bt. LDS: A[128][32] then B[256][32] (one
// array, granule-major == row-major [row][32]).
template <int EP, int BIAS>
__global__ __launch_bounds__(256, 2) void gemm256(const bf16* __restrict__ A, const bf16* __restrict__ B,
                                                  const float* __restrict__ bias, bf16* __restrict__ C,
                                                  int M, int N, int K, int reluLimit) {
    __shared__ __align__(16) bf16 Sm[(128 + 256) * 32];
    const int tid = threadIdx.x, wave = tid >> 6, lane = tid & 63;
    const int m0 = blockIdx.y * 128, n0 = blockIdx.x * 256;

    // 6 staging instructions per wave; 24 total cover 1536 granules
    // granule g (16B): g<512 -> A row g>>2, chunk g&3 ; else B row (g-512)>>2
    const bf16* gp[6];
    bf16* lp[6];
    #pragma unroll
    for (int t = 0; t < 6; t++) {
        int g = (wave * 6 + t) * 64 + lane;
        int isB = g >= 512;
        int r = isB ? ((g - 512) >> 2) : (g >> 2);
        int row = isB ? min(n0 + r, N - 1) : min(m0 + r, M - 1);
        gp[t] = (isB ? B : A) + (size_t)row * K + (lane & 3) * 8;
        lp[t] = Sm + (size_t)(wave * 6 + t) * 512;   // wave-uniform base
    }

    const int wm = (wave >> 1) * 64, wn = (wave & 1) * 128;
    const bf16* fa = Sm + (wm + (lane & 15)) * 32 + (lane >> 4) * 8;
    const bf16* fb = Sm + 4096 + (wn + (lane & 15)) * 32 + (lane >> 4) * 8;

    f32x4 acc[4][8];
    #pragma unroll
    for (int i = 0; i < 4; i++)
        #pragma unroll
        for (int j = 0; j < 8; j++) acc[i][j] = (f32x4){0.f, 0.f, 0.f, 0.f};

    for (int kt = 0; kt < K; kt += 32) {
        __syncthreads();
        #pragma unroll
        for (int t = 0; t < 6; t++) { gload16(gp[t], lp[t]); gp[t] += 32; }
        __syncthreads();
        bf16x8 af[4], bv[8];
        #pragma unroll
        for (int i = 0; i < 4; i++) af[i] = *(const bf16x8*)(fa + i * 16 * 32);
        #pragma unroll
        for (int j = 0; j < 8; j++) bv[j] = *(const bf16x8*)(fb + j * 16 * 32);
        #pragma unroll
        for (int i = 0; i < 4; i++)
            #pragma unroll
            for (int j = 0; j < 8; j++)
                acc[i][j] = __builtin_amdgcn_mfma_f32_16x16x32_bf16(af[i], bv[j], acc[i][j], 0, 0, 0);
    }

    const int mq = (lane >> 4) * 4, nl = lane & 15;
    #pragma unroll
    for (int i = 0; i < 4; i++) {
        #pragma unroll
        for (int j = 0; j < 8; j++) {
            int n = n0 + wn + j * 16 + nl;
            if (n < N) {
                #pragma unroll
                for (int r = 0; r < 4; r++) {
                    int m = m0 + wm + i * 16 + mq + r;
                    if (m < M) {
                        float v = acc[i][j][r];
                        if (BIAS == 1) v += bias[m];
                        else if (BIAS == 2) v += bias[n];
                        if (EP == 1) { if (m < reluLimit) v = fmaxf(v, 0.f); }
                        else if (EP == 2) { v = v / (1.f + __expf(-v)); }
                        C[(size_t)m * N + n] = (bf16)v;
                    }
                }
            }
        }
    }
}

// ---------------------------------------------------------------------------
// token build: T[(b,s)][1152], s=0 global, s=1 time, s>=2 segmented LN(x) adaLN
__global__ __launch_bounds__(256) void build_tok(const float* __restrict__ x, const float* __restrict__ gtok,
                                                 const float* __restrict__ ttok, const bf16* __restrict__ ss,
                                                 const float* __restrict__ sums, bf16* __restrict__ T) {
    int row = blockIdx.x;
    int b = row / SEQ, s = row % SEQ;
    bf16* dst = T + (size_t)row * DD;
    if (s == 0) {
        for (int d = threadIdx.x; d < DD; d += 256) dst[d] = (bf16)gtok[b * DD + d];
        return;
    }
    if (s == 1) {
        for (int d = threadIdx.x; d < DD; d += 256) dst[d] = (bf16)ttok[b * DD + d];
        return;
    }
    float mu = sums[b * 2] * (1.f / (float)NPB);
    float var = sums[b * 2 + 1] * (1.f / (float)NPB) - mu * mu;
    float rsig = rsqrtf(var + 1e-6f);
    int n = s - 2, n1 = n >> 5, n2 = n & 31;
    for (int dd = threadIdx.x; dd < DD; dd += 256) {
        int c = dd >> 2, p1 = (dd >> 1) & 1, p2 = dd & 1;
        int hw = (n1 * 2 + p1) * 64 + n2 * 2 + p2;
        float xv = x[((size_t)b * CC + c) * HW + hw];
        float sc = (float)ss[(size_t)(288 + c) * 16384 + b * HW + hw];
        float sh = (float)ss[(size_t)(0 + c) * 16384 + b * HW + hw];
        dst[dd] = (bf16)((xv - mu) * rsig * (1.f + sc) + sh);
    }
}

// ---------------------------------------------------------------------------
// attention: vk[e][d] = sum_s vpad[s,e]*k[s,d]; grid 144*4 (s-split, atomics)
__global__ __launch_bounds__(256) void attn_vk(const bf16* __restrict__ qkv, float* __restrict__ vk) {
    int bh = blockIdx.x >> 2, sb = blockIdx.x & 3;
    int b = bh / 36, h = bh % 36;
    int s_begin = sb * 288;
    int s_end = min(s_begin + 288, SEQ);
    const bf16* kbase = qkv + (size_t)(DD + h * 32) * RTOT + b * SEQ;
    const bf16* vbase = qkv + (size_t)(2 * DD + h * 32) * RTOT + b * SEQ;
    __shared__ __align__(16) bf16 kk[32][80];
    __shared__ __align__(16) bf16 vv[32][80];
    int tid = threadIdx.x;
    int e = tid >> 3, dg = (tid & 7) * 4;
    int lrow = tid >> 3, lcol = (tid & 7) * 8;
    float a0 = 0.f, a1 = 0.f, a2 = 0.f, a3 = 0.f, aD = 0.f;
    for (int s0 = s_begin; s0 < s_end; s0 += 64) {
        __syncthreads();
        #pragma unroll
        for (int j = 0; j < 8; j++) {
            int s = s0 + lcol + j;
            bool ok = s < s_end;
            kk[lrow][lcol + j] = ok ? kbase[(size_t)lrow * RTOT + s] : (bf16)0.f;
            vv[lrow][lcol + j] = ok ? vbase[(size_t)lrow * RTOT + s] : (bf16)0.f;
        }
        __syncthreads();
        #pragma unroll
        for (int j0 = 0; j0 < 64; j0 += 8) {
            bf16x8 vvv = *(const bf16x8*)&vv[e][j0];
            bf16x8 k0 = *(const bf16x8*)&kk[dg + 0][j0];
            bf16x8 k1 = *(const bf16x8*)&kk[dg + 1][j0];
            bf16x8 k2 = *(const bf16x8*)&kk[dg + 2][j0];
            bf16x8 k3 = *(const bf16x8*)&kk[dg + 3][j0];
            #pragma unroll
            for (int j = 0; j < 8; j++) {
                float vf = (float)vvv[j];
                a0 += vf * (float)k0[j];
                a1 += vf * (float)k1[j];
                a2 += vf * (float)k2[j];
                a3 += vf * (float)k3[j];
            }
            if (tid < 32) {
                bf16x8 kd = *(const bf16x8*)&kk[tid][j0];
                #pragma unroll
                for (int j = 0; j < 8; j++) aD += (float)kd[j];
            }
        }
    }
    float* dst = vk + (size_t)bh * 1056;
    atomicAdd(&dst[e * 32 + dg + 0], a0);
    atomicAdd(&dst[e * 32 + dg + 1], a1);
    atomicAdd(&dst[e * 32 + dg + 2], a2);
    atomicAdd(&dst[e * 32 + dg + 3], a3);
    if (tid < 32) atomicAdd(&dst[1024 + tid], aD);
}

// attention normalize: out[s][e] = (sum_d vk[e][d] q[s][d]) / (den + eps)
__global__ __launch_bounds__(256) void attn_out(const bf16* __restrict__ qkv, const float* __restrict__ vk,
                                                bf16* __restrict__ att) {
    int bh = blockIdx.y, b = bh / 36, h = bh % 36;
    int s0 = blockIdx.x * 64;
    __shared__ float vks[1056];
    __shared__ __align__(16) bf16 qs[32][80];
    int tid = threadIdx.x;
    for (int i = tid; i < 1056; i += 256) vks[i] = vk[(size_t)bh * 1056 + i];
    const bf16* qbase = qkv + (size_t)(h * 32) * RTOT + b * SEQ;
    int lrow = tid >> 3, lcol = (tid & 7) * 8;
    #pragma unroll
    for (int j = 0; j < 8; j++) {
        int s = s0 + lcol + j;
        qs[lrow][lcol + j] = (s < SEQ) ? qbase[(size_t)lrow * RTOT + s] : (bf16)0.f;
    }
    __syncthreads();
    int sl = tid >> 2, eg = (tid & 3) * 8;
    int s = s0 + sl;
    float num[8] = {0.f, 0.f, 0.f, 0.f, 0.f, 0.f, 0.f, 0.f};
    float den = 0.f;
    #pragma unroll
    for (int d = 0; d < 32; d++) {
        float qv = (float)qs[d][sl];
        den += vks[1024 + d] * qv;
        #pragma unroll
        for (int t = 0; t < 8; t++) num[t] += vks[(eg + t) * 32 + d] * qv;
    }
    if (s < SEQ) {
        float inv = 1.f / (den + 1e-8f);
        bf16* dst = att + ((size_t)(b * SEQ + s)) * DD + h * 32 + eg;
        #pragma unroll
        for (int t = 0; t < 8; t++) dst[t] = (bf16)(num[t] * inv);
    }
}

// ---------------------------------------------------------------------------
// x1 = x + comb(aproj)*g_msa -> d_out (fp32), LN2 partials (no atomics)
__global__ __launch_bounds__(256) void add_attn(const float* __restrict__ x, const bf16* __restrict__ aproj,
                                                const bf16* __restrict__ ss, float* __restrict__ xo,
                                                float* __restrict__ part) {
    int b = blockIdx.x / 4608;
    size_t idx = (size_t)blockIdx.x * 256 + threadIdx.x;
    size_t local = idx - (size_t)b * NPB;
    int c = (int)(local >> 12), hw = (int)(local & 4095);
    int hh = hw >> 6, w = hw & 63;
    int n = (hh >> 1) * 32 + (w >> 1);
    int dd = c * 4 + (hh & 1) * 2 + (w & 1);
    float a = (float)aproj[(size_t)dd * RTOT + b * SEQ + 2 + n];
    float g = (float)ss[(size_t)(576 + c) * 16384 + b * HW + hw];
    float v = x[idx] + a * g;
    xo[idx] = v;
    block_reduce2_store(v, v * v, part + (size_t)blockIdx.x * 2);
}

// tok2 build (no extra tokens)
__global__ __launch_bounds__(256) void build_tok2(const float* __restrict__ x1, const bf16* __restrict__ ss,
                                                  const float* __restrict__ sums, bf16* __restrict__ T2) {
    int row = blockIdx.x, b = row >> 10, n = row & 1023;
    float mu = sums[8 + b * 2] * (1.f / (float)NPB);
    float var = sums[9 + b * 2] * (1.f / (float)NPB) - mu * mu;
    float rsig = rsqrtf(var + 1e-6f);
    int n1 = n >> 5, n2 = n & 31;
    bf16* dst = T2 + (size_t)row * DD;
    for (int dd = threadIdx.x; dd < DD; dd += 256) {
        int c = dd >> 2, p1 = (dd >> 1) & 1, p2 = dd & 1;
        int hw = (n1 * 2 + p1) * 64 + n2 * 2 + p2;
        float xv = x1[((size_t)b * CC + c) * HW + hw];
        float sc = (float)ss[(size_t)(1152 + c) * 16384 + b * HW + hw];
        float sh = (float)ss[(size_t)(864 + c) * 16384 + b * HW + hw];
        dst[dd] = (bf16)((xv - mu) * rsig * (1.f + sc) + sh);
    }
}

// ---------------------------------------------------------------------------
// depthwise 3x3 + bias + GLU. grid (72 cchunk, 16 tile, 4 b), block 256.
__global__ __launch_bounds__(256) void dwglu(const bf16* __restrict__ y, const float* __restrict__ dw_w,
                                             const float* __restrict__ dw_b, bf16* __restrict__ g) {
    __shared__ __align__(16) bf16 xs[6400];
    __shared__ __align__(16) bf16 gs[6400];
    int b = blockIdx.z, tile = blockIdx.y, c0 = blockIdx.x * 64;
    int ty = (tile >> 2) * 8, tx = (tile & 3) * 8;
    int tid = threadIdx.x, cc = tid & 63, pg = tid >> 6;
    for (int p = pg; p < 100; p += 4) {
        int py = ty + p / 10 - 1, px = tx + p % 10 - 1;
        bool in = (py >= 0 && py < 32 && px >= 0 && px < 32);
        size_t base = ((size_t)(b * NTOK + py * 32 + px)) * HF2;
        xs[p * 64 + cc] = in ? y[base + c0 + cc] : (bf16)0.f;
        gs[p * 64 + cc] = in ? y[base + HF + c0 + cc] : (bf16)0.f;
    }
    float wx[9], wg[9];
    #pragma unroll
    for (int t = 0; t < 9; t++) {
        wx[t] = dw_w[(size_t)(c0 + cc) * 9 + t];
        wg[t] = dw_w[(size_t)(HF + c0 + cc) * 9 + t];
    }
    float bx = dw_b[c0 + cc], bg = dw_b[HF + c0 + cc];
    __syncthreads();
    for (int p = pg * 16; p < pg * 16 + 16; p++) {
        int py = p >> 3, px = p & 7;
        float ax = bx, ag = bg;
        #pragma unroll
        for (int dy = 0; dy < 3; dy++)
            #pragma unroll
            for (int dx = 0; dx < 3; dx++) {
                int q = (py + dy) * 10 + (px + dx);
                ax += (float)xs[q * 64 + cc] * wx[dy * 3 + dx];
                ag += (float)gs[q * 64 + cc] * wg[dy * 3 + dx];
            }
        float out = ax * (ag / (1.f + __expf(-ag)));
        g[((size_t)(b * NTOK + (ty + py) * 32 + tx + px)) * HF + c0 + cc] = (bf16)out;
    }
}

// final: out = x1 + comb(m)*g_mlp
__global__ __launch_bounds__(256) void add_mlp(const bf16* __restrict__ mm, const bf16* __restrict__ ss,
                                               float* __restrict__ xo) {
    int b = blockIdx.x / 4608;
    size_t idx = (size_t)blockIdx.x * 256 + threadIdx.x;
    size_t local = idx - (size_t)b * NPB;
    int c = (int)(local >> 12), hw = (int)(local & 4095);
    int hh = hw >> 6, w = hw & 63;
    int n = (hh >> 1) * 32 + (w >> 1);
    int dd = c * 4 + (hh & 1) * 2 + (w & 1);
    float mv = (float)mm[(size_t)dd * 4096 + b * NTOK + n];
    float g = (float)ss[(size_t)(1440 + c) * 16384 + b * HW + hw];
    xo[idx] = xo[idx] + mv * g;
}

// ---------------------------------------------------------------------------
extern "C" void kernel_launch(void* const* d_in, const int* in_sizes, int n_in,
                              void* d_out, int out_size, void* d_ws, size_t ws_size,
                              hipStream_t stream) {
    (void)in_sizes; (void)n_in; (void)out_size; (void)ws_size;
    const float* x      = (const float*)d_in[0];
    const float* cond   = (const float*)d_in[1];
    const float* gtok   = (const float*)d_in[2];
    const float* ttok   = (const float*)d_in[3];
    const float* ss_w   = (const float*)d_in[4];
    const float* ss_b   = (const float*)d_in[5];
    const float* qkv_w  = (const float*)d_in[6];
    const float* proj_w = (const float*)d_in[7];
    const float* proj_b = (const float*)d_in[8];
    const float* inv_w  = (const float*)d_in[9];
    const float* inv_b  = (const float*)d_in[10];
    const float* dw_w   = (const float*)d_in[11];
    const float* dw_b   = (const float*)d_in[12];
    const float* pw_w   = (const float*)d_in[13];
    float* out = (float*)d_out;
    char* ws = (char*)d_ws;

    float* sums  = (float*)(ws + OFF_SUMS);
    float* PART1 = (float*)(ws + OFF_PART1);
    float* PART2 = (float*)(ws + OFF_PART2);
    bf16* SS    = (bf16*)(ws + OFF_SS);
    bf16* A1    = (bf16*)(ws + OFF_A1);
    bf16* T     = (bf16*)(ws + OFF_T);
    bf16* QKV   = (bf16*)(ws + OFF_QKV);
    float* VK   = (float*)(ws + OFF_VK);
    bf16* ATT   = (bf16*)(ws + OFF_ATT);
    bf16* APROJ = (bf16*)(ws + OFF_APROJ);
    bf16* T2    = (bf16*)(ws + OFF_T2);
    bf16* Y     = (bf16*)(ws + OFF_Y);
    bf16* G     = (bf16*)(ws + OFF_G);
    bf16* MM    = (bf16*)(ws + OFF_M);
    bf16* WSS   = (bf16*)(ws + OFF_WSS);
    bf16* WQKV  = (bf16*)(ws + OFF_WQKV);
    bf16* WPROJ = (bf16*)(ws + OFF_WPROJ);
    bf16* WINV  = (bf16*)(ws + OFF_WINV);
    bf16* WPW   = (bf16*)(ws + OFF_WPW);

    cvt_bf16<<<2916, 256, 0, stream>>>(ss_w, WSS, C6 * C6 / 4);
    cvt_bf16<<<3888, 256, 0, stream>>>(qkv_w, WQKV, 3456 * DD / 4);
    cvt_bf16<<<1296, 256, 0, stream>>>(proj_w, WPROJ, DD * DD / 4);
    cvt_bf16<<<10368, 256, 0, stream>>>(inv_w, WINV, HF2 * DD / 4);
    cvt_bf16<<<5184, 256, 0, stream>>>(pw_w, WPW, DD * HF / 4);

    // LN1 stats: per-block partials (PART1 overlays A1; consumed before prep_cond)
    ln_stats<<<1152, 256, 0, stream>>>(x, PART1);
    reduce_part<<<4, 256, 0, stream>>>(PART1, sums, 288, 0);
    prep_cond<<<dim3(64, 27, 4), 256, 0, stream>>>(cond, A1);
    // ss = silu(cond) @ ss_w^T + ss_b, out [o][16384]  (128x256 tiles)
    gemm256<0, 1><<<dim3(64, 14), 256, 0, stream>>>(WSS, A1, ss_b, SS, C6, 16384, C6, 0);
    build_tok<<<RTOT, 256, 0, stream>>>(x, gtok, ttok, SS, sums, T);
    // qkv, relu on first 2304 output channels  (128x256 tiles)
    gemm256<1, 0><<<dim3(17, 27), 256, 0, stream>>>(WQKV, T, nullptr, QKV, 3456, RTOT, DD, 2304);
    hipMemsetAsync(ws + OFF_VK, 0, (size_t)144 * 1056 * 4, stream);
    attn_vk<<<576, 256, 0, stream>>>(QKV, VK);
    attn_out<<<dim3(17, 144), 256, 0, stream>>>(QKV, VK, ATT);
    // proj (small grid -> keep 128x128)
    gemm_bt<0, 1><<<dim3(33, 9), 256, 0, stream>>>(WPROJ, ATT, proj_b, APROJ, DD, RTOT, DD, 0);
    // x1 + LN2 partials (PART2 overlays dead QKV region)
    add_attn<<<18432, 256, 0, stream>>>(x, APROJ, SS, out, PART2);
    reduce_part<<<4, 256, 0, stream>>>(PART2, sums, 4608, 8);
    build_tok2<<<4096, 256, 0, stream>>>(out, SS, sums, T2);
    // MLP expand + silu, out [r][9216]  (128x256 tiles)
    gemm256<2, 2><<<dim3(36, 32), 256, 0, stream>>>(T2, WINV, inv_b, Y, 4096, HF2, DD, 0);
    dwglu<<<dim3(72, 16, 4), 256, 0, stream>>>(Y, dw_w, dw_b, G);
    // MLP project, out [o][4096] (small grid -> keep 128x128)
    gemm_bt<0, 0><<<dim3(32, 9), 256, 0, stream>>>(WPW, G, nullptr, MM, DD, 4096, HF, 0);
    add_mlp<<<18432, 256, 0, stream>>>(MM, SS, out);
}

// Round 4
// 1137.753 us; speedup vs baseline: 1.0174x; 1.0174x over previous
//
#include <hip/hip_runtime.h>
#include <hip/hip_bf16.h>
#include <cstdint>

// ---------------------------------------------------------------------------
// SANA MS-AdaLN block on MI355X.
// R1: LN stats via per-block partials (atomic serialization fix).
// R3 post-mortem: 128x256 tile regressed (2 waves/SIMD residency < 3; matches
//   guide's measured tile-space: 128^2 is the sweet spot). Reverted.
// R4: XOR-swizzle LDS chunk index in gemm_bt (s(r)=(r&3)^((r>>2)&3)) to kill
//   the 8-way bank conflicts on ds_read_b128 fragment reads (1.24e7
//   SQ_LDS_BANK_CONFLICT/dispatch = ~4 extra cyc/read on the limiting pipe).
// ---------------------------------------------------------------------------

typedef __bf16 bf16;
typedef bf16 bf16x8 __attribute__((ext_vector_type(8)));
typedef bf16 bf16x4 __attribute__((ext_vector_type(4)));
typedef float f32x4 __attribute__((ext_vector_type(4)));

typedef const __attribute__((address_space(1))) void gas_void;
typedef __attribute__((address_space(3))) void las_void;

__device__ __forceinline__ void gload16(const bf16* g, bf16* l) {
    __builtin_amdgcn_global_load_lds((gas_void*)g, (las_void*)l, 16, 0, 0);
}

// ---- problem constants ----
#define BB 4
#define CC 288
#define HW 4096          // 64*64
#define C6 1728
#define DD 1152
#define SEQ 1026
#define RTOT 4104        // 4*1026
#define NTOK 1024
#define HF 4608
#define HF2 9216
#define NPB 1179648      // elements per batch sample (288*4096)

// ---- workspace layout (bytes) ----
static constexpr size_t OFF_SUMS = 0;                                   // 16 floats
static constexpr size_t OFF_SS   = 256;                                 // bf16 [1728][16384]
static constexpr size_t SS_BYTES = (size_t)C6 * 16384 * 2;              // 56,623,104
static constexpr size_t OFF_R2   = OFF_SS + SS_BYTES;
// phase A
static constexpr size_t OFF_PART1= OFF_R2;                              // f32 [1152][2] (dead before prep_cond)
static constexpr size_t OFF_A1   = OFF_R2;                              // bf16 [16384][1728]
// phase B (A1 dead after GEMM1)
static constexpr size_t OFF_T    = OFF_R2;                              // bf16 [4104][1152]
static constexpr size_t OFF_QKV  = OFF_T   + (size_t)RTOT*DD*2;         // bf16 [3456][4104]
static constexpr size_t OFF_PART2= OFF_QKV;                             // f32 [18432][2] (QKV dead at add_attn)
static constexpr size_t OFF_VK   = OFF_QKV + (size_t)3456*RTOT*2;       // f32  [144][1056]
static constexpr size_t OFF_ATT  = OFF_VK  + (size_t)144*1056*4;        // bf16 [4104][1152]
static constexpr size_t OFF_APROJ= OFF_ATT + (size_t)RTOT*DD*2;         // bf16 [1152][4104]
// phase C (phase B dead after add_attn)
static constexpr size_t OFF_T2   = OFF_R2;                              // bf16 [4096][1152]
static constexpr size_t OFF_Y    = OFF_T2  + (size_t)4096*DD*2;         // bf16 [4096][9216]
static constexpr size_t OFF_G    = OFF_Y   + (size_t)4096*HF2*2;        // bf16 [4096][4608]
static constexpr size_t OFF_M    = OFF_G   + (size_t)4096*HF*2;         // bf16 [1152][4096]
// converted weights (persistent)
static constexpr size_t OFF_W    = OFF_R2  + 132120576;                 // end of phase C
static constexpr size_t OFF_WSS  = OFF_W;
static constexpr size_t OFF_WQKV = OFF_WSS  + (size_t)C6*C6*2;
static constexpr size_t OFF_WPROJ= OFF_WQKV + (size_t)3456*DD*2;
static constexpr size_t OFF_WINV = OFF_WPROJ+ (size_t)DD*DD*2;
static constexpr size_t OFF_WPW  = OFF_WINV + (size_t)HF2*DD*2;

// ---------------------------------------------------------------------------
// fp32 -> bf16 weight conversion
__global__ __launch_bounds__(256) void cvt_bf16(const float* __restrict__ s,
                                                bf16* __restrict__ d, int n4) {
    int i = blockIdx.x * 256 + threadIdx.x;
    if (i < n4) {
        float4 v = ((const float4*)s)[i];
        bf16x4 o = {(bf16)v.x, (bf16)v.y, (bf16)v.z, (bf16)v.w};
        ((bf16x4*)d)[i] = o;
    }
}

// ---------------------------------------------------------------------------
// block reduce (sum, sumsq); thread 0 stores 2 floats (no atomics)
__device__ __forceinline__ void block_reduce2_store(float s1, float s2, float* dst) {
    #pragma unroll
    for (int o = 32; o > 0; o >>= 1) { s1 += __shfl_down(s1, o); s2 += __shfl_down(s2, o); }
    __shared__ float r1[4], r2[4];
    int wave = threadIdx.x >> 6, lane = threadIdx.x & 63;
    if (lane == 0) { r1[wave] = s1; r2[wave] = s2; }
    __syncthreads();
    if (threadIdx.x == 0) {
        dst[0] = r1[0] + r1[1] + r1[2] + r1[3];
        dst[1] = r2[0] + r2[1] + r2[2] + r2[3];
    }
}

// LN1 stats over x: grid 4*288 blocks, 4096 elems/block -> partials
__global__ __launch_bounds__(256) void ln_stats(const float* __restrict__ x, float* __restrict__ part) {
    const float* base = x + (size_t)blockIdx.x * 4096;
    float s1 = 0.f, s2 = 0.f;
    #pragma unroll
    for (int it = 0; it < 4; it++) {
        float4 v = ((const float4*)base)[it * 256 + threadIdx.x];
        s1 += v.x + v.y + v.z + v.w;
        s2 += v.x * v.x + v.y * v.y + v.z * v.z + v.w * v.w;
    }
    block_reduce2_store(s1, s2, part + (size_t)blockIdx.x * 2);
}

// collapse per-block partials -> sums[out_off + b*2 .. +1]. grid = 4 (one per batch)
__global__ __launch_bounds__(256) void reduce_part(const float* __restrict__ part, float* __restrict__ sums,
                                                   int nper, int out_off) {
    int b = blockIdx.x;
    float s1 = 0.f, s2 = 0.f;
    for (int i = threadIdx.x; i < nper; i += 256) {
        s1 += part[(size_t)(b * nper + i) * 2];
        s2 += part[(size_t)(b * nper + i) * 2 + 1];
    }
    block_reduce2_store(s1, s2, sums + out_off + b * 2);
}

// ---------------------------------------------------------------------------
// silu(cond) transpose: (b, k, hw) f32 -> A1[(b,hw)][k] bf16. grid (64,27,4)
__global__ __launch_bounds__(256) void prep_cond(const float* __restrict__ cond, bf16* __restrict__ A1) {
    __shared__ float tile[64][65];
    int b = blockIdx.z, k0 = blockIdx.y * 64, h0 = blockIdx.x * 64;
    int col = threadIdx.x & 63, r4 = threadIdx.x >> 6;
    const float* src = cond + ((size_t)b * C6 + k0) * HW + h0;
    #pragma unroll
    for (int p = 0; p < 16; p++) {
        int kk = r4 + p * 4;
        float v = src[(size_t)kk * HW + col];
        tile[col][kk] = v / (1.f + __expf(-v));
    }
    __syncthreads();
    bf16* dst = A1 + ((size_t)(b * HW + h0)) * C6 + k0;
    #pragma unroll
    for (int p = 0; p < 16; p++) {
        int rr = r4 + p * 4;
        dst[(size_t)rr * C6 + col] = (bf16)tile[rr][col];
    }
}

// ---------------------------------------------------------------------------
// gemm_bt: C[m][n] = sum_k A[m][k]*B[n][k]  (both operands k-contiguous bf16)
// EP: 0=none, 1=relu if m<reluLimit, 2=silu.  BIAS: 0=none, 1=per-m, 2=per-n.
// LDS layout XOR-swizzled: data (row r, 16B-chunk c) lives at granule
// r*4 + (c ^ s(r)), s(r) = (r&3)^((r>>2)&3)  -> conflict-free ds_read_b128.
template <int EP, int BIAS>
__global__ __launch_bounds__(256) void gemm_bt(const bf16* __restrict__ A, const bf16* __restrict__ B,
                                               const float* __restrict__ bias, bf16* __restrict__ C,
                                               int M, int N, int K, int reluLimit) {
    __shared__ __align__(16) bf16 As[128 * 32];
    __shared__ __align__(16) bf16 Bs[128 * 32];
    const int tid = threadIdx.x, wave = tid >> 6, lane = tid & 63;
    const int m0 = blockIdx.y * 128, n0 = blockIdx.x * 128;

    const int c0 = wave * 128 + lane;          // granule id [0,512)
    const int c1 = c0 + 64;                    // rows +16, same chunk & swizzle
    // swizzle: s depends on row = c>>2; period 16 -> identical for c0,c1
    const int sw = ((c0 >> 2) & 3) ^ ((c0 >> 4) & 3);
    const int ka = (((c0 & 3) ^ sw)) * 8;      // swizzled global chunk (elements)
    int ra0 = min(m0 + (c0 >> 2), M - 1), ra1 = min(m0 + (c1 >> 2), M - 1);
    int rb0 = min(n0 + (c0 >> 2), N - 1), rb1 = min(n0 + (c1 >> 2), N - 1);
    const bf16* gA0 = A + (size_t)ra0 * K + ka;
    const bf16* gA1 = A + (size_t)ra1 * K + ka;
    const bf16* gB0 = B + (size_t)rb0 * K + ka;
    const bf16* gB1 = B + (size_t)rb1 * K + ka;
    bf16* lA0 = As + wave * 1024;
    bf16* lA1 = As + wave * 1024 + 512;
    bf16* lB0 = Bs + wave * 1024;
    bf16* lB1 = Bs + wave * 1024 + 512;

    const int wm = (wave >> 1) * 64, wn = (wave & 1) * 64;
    const int l15 = lane & 15;
    const int sr = (l15 & 3) ^ ((l15 >> 2) & 3);           // s(row) for frag rows
    const int fc = ((lane >> 4) ^ sr) * 8;                 // swizzled chunk offset
    const bf16* fa = As + (wm + l15) * 32 + fc;
    const bf16* fb = Bs + (wn + l15) * 32 + fc;

    f32x4 acc[4][4];
    #pragma unroll
    for (int i = 0; i < 4; i++)
        #pragma unroll
        for (int j = 0; j < 4; j++) acc[i][j] = (f32x4){0.f, 0.f, 0.f, 0.f};

    for (int kt = 0; kt < K; kt += 32) {
        __syncthreads();
        gload16(gA0, lA0); gload16(gA1, lA1);
        gload16(gB0, lB0); gload16(gB1, lB1);
        gA0 += 32; gA1 += 32; gB0 += 32; gB1 += 32;
        __syncthreads();
        bf16x8 af[4], bv[4];
        #pragma unroll
        for (int i = 0; i < 4; i++) af[i] = *(const bf16x8*)(fa + i * 16 * 32);
        #pragma unroll
        for (int j = 0; j < 4; j++) bv[j] = *(const bf16x8*)(fb + j * 16 * 32);
        #pragma unroll
        for (int i = 0; i < 4; i++)
            #pragma unroll
            for (int j = 0; j < 4; j++)
                acc[i][j] = __builtin_amdgcn_mfma_f32_16x16x32_bf16(af[i], bv[j], acc[i][j], 0, 0, 0);
    }

    const int mq = (lane >> 4) * 4, nl = lane & 15;
    #pragma unroll
    for (int i = 0; i < 4; i++) {
        #pragma unroll
        for (int j = 0; j < 4; j++) {
            int n = n0 + wn + j * 16 + nl;
            if (n < N) {
                #pragma unroll
                for (int r = 0; r < 4; r++) {
                    int m = m0 + wm + i * 16 + mq + r;
                    if (m < M) {
                        float v = acc[i][j][r];
                        if (BIAS == 1) v += bias[m];
                        else if (BIAS == 2) v += bias[n];
                        if (EP == 1) { if (m < reluLimit) v = fmaxf(v, 0.f); }
                        else if (EP == 2) { v = v / (1.f + __expf(-v)); }
                        C[(size_t)m * N + n] = (bf16)v;
                    }
                }
            }
        }
    }
}

// ---------------------------------------------------------------------------
// token build: T[(b,s)][1152], s=0 global, s=1 time, s>=2 segmented LN(x) adaLN
__global__ __launch_bounds__(256) void build_tok(const float* __restrict__ x, const float* __restrict__ gtok,
                                                 const float* __restrict__ ttok, const bf16* __restrict__ ss,
                                                 const float* __restrict__ sums, bf16* __restrict__ T) {
    int row = blockIdx.x;
    int b = row / SEQ, s = row % SEQ;
    bf16* dst = T + (size_t)row * DD;
    if (s == 0) {
        for (int d = threadIdx.x; d < DD; d += 256) dst[d] = (bf16)gtok[b * DD + d];
        return;
    }
    if (s == 1) {
        for (int d = threadIdx.x; d < DD; d += 256) dst[d] = (bf16)ttok[b * DD + d];
        return;
    }
    float mu = sums[b * 2] * (1.f / (float)NPB);
    float var = sums[b * 2 + 1] * (1.f / (float)NPB) - mu * mu;
    float rsig = rsqrtf(var + 1e-6f);
    int n = s - 2, n1 = n >> 5, n2 = n & 31;
    for (int dd = threadIdx.x; dd < DD; dd += 256) {
        int c = dd >> 2, p1 = (dd >> 1) & 1, p2 = dd & 1;
        int hw = (n1 * 2 + p1) * 64 + n2 * 2 + p2;
        float xv = x[((size_t)b * CC + c) * HW + hw];
        float sc = (float)ss[(size_t)(288 + c) * 16384 + b * HW + hw];
        float sh = (float)ss[(size_t)(0 + c) * 16384 + b * HW + hw];
        dst[dd] = (bf16)((xv - mu) * rsig * (1.f + sc) + sh);
    }
}

// ---------------------------------------------------------------------------
// attention: vk[e][d] = sum_s vpad[s,e]*k[s,d]; grid 144*4 (s-split, atomics)
__global__ __launch_bounds__(256) void attn_vk(const bf16* __restrict__ qkv, float* __restrict__ vk) {
    int bh = blockIdx.x >> 2, sb = blockIdx.x & 3;
    int b = bh / 36, h = bh % 36;
    int s_begin = sb * 288;
    int s_end = min(s_begin + 288, SEQ);
    const bf16* kbase = qkv + (size_t)(DD + h * 32) * RTOT + b * SEQ;
    const bf16* vbase = qkv + (size_t)(2 * DD + h * 32) * RTOT + b * SEQ;
    __shared__ __align__(16) bf16 kk[32][80];
    __shared__ __align__(16) bf16 vv[32][80];
    int tid = threadIdx.x;
    int e = tid >> 3, dg = (tid & 7) * 4;
    int lrow = tid >> 3, lcol = (tid & 7) * 8;
    float a0 = 0.f, a1 = 0.f, a2 = 0.f, a3 = 0.f, aD = 0.f;
    for (int s0 = s_begin; s0 < s_end; s0 += 64) {
        __syncthreads();
        #pragma unroll
        for (int j = 0; j < 8; j++) {
            int s = s0 + lcol + j;
            bool ok = s < s_end;
            kk[lrow][lcol + j] = ok ? kbase[(size_t)lrow * RTOT + s] : (bf16)0.f;
            vv[lrow][lcol + j] = ok ? vbase[(size_t)lrow * RTOT + s] : (bf16)0.f;
        }
        __syncthreads();
        #pragma unroll
        for (int j0 = 0; j0 < 64; j0 += 8) {
            bf16x8 vvv = *(const bf16x8*)&vv[e][j0];
            bf16x8 k0 = *(const bf16x8*)&kk[dg + 0][j0];
            bf16x8 k1 = *(const bf16x8*)&kk[dg + 1][j0];
            bf16x8 k2 = *(const bf16x8*)&kk[dg + 2][j0];
            bf16x8 k3 = *(const bf16x8*)&kk[dg + 3][j0];
            #pragma unroll
            for (int j = 0; j < 8; j++) {
                float vf = (float)vvv[j];
                a0 += vf * (float)k0[j];
                a1 += vf * (float)k1[j];
                a2 += vf * (float)k2[j];
                a3 += vf * (float)k3[j];
            }
            if (tid < 32) {
                bf16x8 kd = *(const bf16x8*)&kk[tid][j0];
                #pragma unroll
                for (int j = 0; j < 8; j++) aD += (float)kd[j];
            }
        }
    }
    float* dst = vk + (size_t)bh * 1056;
    atomicAdd(&dst[e * 32 + dg + 0], a0);
    atomicAdd(&dst[e * 32 + dg + 1], a1);
    atomicAdd(&dst[e * 32 + dg + 2], a2);
    atomicAdd(&dst[e * 32 + dg + 3], a3);
    if (tid < 32) atomicAdd(&dst[1024 + tid], aD);
}

// attention normalize: out[s][e] = (sum_d vk[e][d] q[s][d]) / (den + eps)
__global__ __launch_bounds__(256) void attn_out(const bf16* __restrict__ qkv, const float* __restrict__ vk,
                                                bf16* __restrict__ att) {
    int bh = blockIdx.y, b = bh / 36, h = bh % 36;
    int s0 = blockIdx.x * 64;
    __shared__ float vks[1056];
    __shared__ __align__(16) bf16 qs[32][80];
    int tid = threadIdx.x;
    for (int i = tid; i < 1056; i += 256) vks[i] = vk[(size_t)bh * 1056 + i];
    const bf16* qbase = qkv + (size_t)(h * 32) * RTOT + b * SEQ;
    int lrow = tid >> 3, lcol = (tid & 7) * 8;
    #pragma unroll
    for (int j = 0; j < 8; j++) {
        int s = s0 + lcol + j;
        qs[lrow][lcol + j] = (s < SEQ) ? qbase[(size_t)lrow * RTOT + s] : (bf16)0.f;
    }
    __syncthreads();
    int sl = tid >> 2, eg = (tid & 3) * 8;
    int s = s0 + sl;
    float num[8] = {0.f, 0.f, 0.f, 0.f, 0.f, 0.f, 0.f, 0.f};
    float den = 0.f;
    #pragma unroll
    for (int d = 0; d < 32; d++) {
        float qv = (float)qs[d][sl];
        den += vks[1024 + d] * qv;
        #pragma unroll
        for (int t = 0; t < 8; t++) num[t] += vks[(eg + t) * 32 + d] * qv;
    }
    if (s < SEQ) {
        float inv = 1.f / (den + 1e-8f);
        bf16* dst = att + ((size_t)(b * SEQ + s)) * DD + h * 32 + eg;
        #pragma unroll
        for (int t = 0; t < 8; t++) dst[t] = (bf16)(num[t] * inv);
    }
}

// ---------------------------------------------------------------------------
// x1 = x + comb(aproj)*g_msa -> d_out (fp32), LN2 partials (no atomics)
__global__ __launch_bounds__(256) void add_attn(const float* __restrict__ x, const bf16* __restrict__ aproj,
                                                const bf16* __restrict__ ss, float* __restrict__ xo,
                                                float* __restrict__ part) {
    int b = blockIdx.x / 4608;
    size_t idx = (size_t)blockIdx.x * 256 + threadIdx.x;
    size_t local = idx - (size_t)b * NPB;
    int c = (int)(local >> 12), hw = (int)(local & 4095);
    int hh = hw >> 6, w = hw & 63;
    int n = (hh >> 1) * 32 + (w >> 1);
    int dd = c * 4 + (hh & 1) * 2 + (w & 1);
    float a = (float)aproj[(size_t)dd * RTOT + b * SEQ + 2 + n];
    float g = (float)ss[(size_t)(576 + c) * 16384 + b * HW + hw];
    float v = x[idx] + a * g;
    xo[idx] = v;
    block_reduce2_store(v, v * v, part + (size_t)blockIdx.x * 2);
}

// tok2 build (no extra tokens)
__global__ __launch_bounds__(256) void build_tok2(const float* __restrict__ x1, const bf16* __restrict__ ss,
                                                  const float* __restrict__ sums, bf16* __restrict__ T2) {
    int row = blockIdx.x, b = row >> 10, n = row & 1023;
    float mu = sums[8 + b * 2] * (1.f / (float)NPB);
    float var = sums[9 + b * 2] * (1.f / (float)NPB) - mu * mu;
    float rsig = rsqrtf(var + 1e-6f);
    int n1 = n >> 5, n2 = n & 31;
    bf16* dst = T2 + (size_t)row * DD;
    for (int dd = threadIdx.x; dd < DD; dd += 256) {
        int c = dd >> 2, p1 = (dd >> 1) & 1, p2 = dd & 1;
        int hw = (n1 * 2 + p1) * 64 + n2 * 2 + p2;
        float xv = x1[((size_t)b * CC + c) * HW + hw];
        float sc = (float)ss[(size_t)(1152 + c) * 16384 + b * HW + hw];
        float sh = (float)ss[(size_t)(864 + c) * 16384 + b * HW + hw];
        dst[dd] = (bf16)((xv - mu) * rsig * (1.f + sc) + sh);
    }
}

// ---------------------------------------------------------------------------
// depthwise 3x3 + bias + GLU. grid (72 cchunk, 16 tile, 4 b), block 256.
__global__ __launch_bounds__(256) void dwglu(const bf16* __restrict__ y, const float* __restrict__ dw_w,
                                             const float* __restrict__ dw_b, bf16* __restrict__ g) {
    __shared__ __align__(16) bf16 xs[6400];
    __shared__ __align__(16) bf16 gs[6400];
    int b = blockIdx.z, tile = blockIdx.y, c0 = blockIdx.x * 64;
    int ty = (tile >> 2) * 8, tx = (tile & 3) * 8;
    int tid = threadIdx.x, cc = tid & 63, pg = tid >> 6;
    for (int p = pg; p < 100; p += 4) {
        int py = ty + p / 10 - 1, px = tx + p % 10 - 1;
        bool in = (py >= 0 && py < 32 && px >= 0 && px < 32);
        size_t base = ((size_t)(b * NTOK + py * 32 + px)) * HF2;
        xs[p * 64 + cc] = in ? y[base + c0 + cc] : (bf16)0.f;
        gs[p * 64 + cc] = in ? y[base + HF + c0 + cc] : (bf16)0.f;
    }
    float wx[9], wg[9];
    #pragma unroll
    for (int t = 0; t < 9; t++) {
        wx[t] = dw_w[(size_t)(c0 + cc) * 9 + t];
        wg[t] = dw_w[(size_t)(HF + c0 + cc) * 9 + t];
    }
    float bx = dw_b[c0 + cc], bg = dw_b[HF + c0 + cc];
    __syncthreads();
    for (int p = pg * 16; p < pg * 16 + 16; p++) {
        int py = p >> 3, px = p & 7;
        float ax = bx, ag = bg;
        #pragma unroll
        for (int dy = 0; dy < 3; dy++)
            #pragma unroll
            for (int dx = 0; dx < 3; dx++) {
                int q = (py + dy) * 10 + (px + dx);
                ax += (float)xs[q * 64 + cc] * wx[dy * 3 + dx];
                ag += (float)gs[q * 64 + cc] * wg[dy * 3 + dx];
            }
        float out = ax * (ag / (1.f + __expf(-ag)));
        g[((size_t)(b * NTOK + (ty + py) * 32 + tx + px)) * HF + c0 + cc] = (bf16)out;
    }
}

// final: out = x1 + comb(m)*g_mlp
__global__ __launch_bounds__(256) void add_mlp(const bf16* __restrict__ mm, const bf16* __restrict__ ss,
                                               float* __restrict__ xo) {
    int b = blockIdx.x / 4608;
    size_t idx = (size_t)blockIdx.x * 256 + threadIdx.x;
    size_t local = idx - (size_t)b * NPB;
    int c = (int)(local >> 12), hw = (int)(local & 4095);
    int hh = hw >> 6, w = hw & 63;
    int n = (hh >> 1) * 32 + (w >> 1);
    int dd = c * 4 + (hh & 1) * 2 + (w & 1);
    float mv = (float)mm[(size_t)dd * 4096 + b * NTOK + n];
    float g = (float)ss[(size_t)(1440 + c) * 16384 + b * HW + hw];
    xo[idx] = xo[idx] + mv * g;
}

// ---------------------------------------------------------------------------
extern "C" void kernel_launch(void* const* d_in, const int* in_sizes, int n_in,
                              void* d_out, int out_size, void* d_ws, size_t ws_size,
                              hipStream_t stream) {
    (void)in_sizes; (void)n_in; (void)out_size; (void)ws_size;
    const float* x      = (const float*)d_in[0];
    const float* cond   = (const float*)d_in[1];
    const float* gtok   = (const float*)d_in[2];
    const float* ttok   = (const float*)d_in[3];
    const float* ss_w   = (const float*)d_in[4];
    const float* ss_b   = (const float*)d_in[5];
    const float* qkv_w  = (const float*)d_in[6];
    const float* proj_w = (const float*)d_in[7];
    const float* proj_b = (const float*)d_in[8];
    const float* inv_w  = (const float*)d_in[9];
    const float* inv_b  = (const float*)d_in[10];
    const float* dw_w   = (const float*)d_in[11];
    const float* dw_b   = (const float*)d_in[12];
    const float* pw_w   = (const float*)d_in[13];
    float* out = (float*)d_out;
    char* ws = (char*)d_ws;

    float* sums  = (float*)(ws + OFF_SUMS);
    float* PART1 = (float*)(ws + OFF_PART1);
    float* PART2 = (float*)(ws + OFF_PART2);
    bf16* SS    = (bf16*)(ws + OFF_SS);
    bf16* A1    = (bf16*)(ws + OFF_A1);
    bf16* T     = (bf16*)(ws + OFF_T);
    bf16* QKV   = (bf16*)(ws + OFF_QKV);
    float* VK   = (float*)(ws + OFF_VK);
    bf16* ATT   = (bf16*)(ws + OFF_ATT);
    bf16* APROJ = (bf16*)(ws + OFF_APROJ);
    bf16* T2    = (bf16*)(ws + OFF_T2);
    bf16* Y     = (bf16*)(ws + OFF_Y);
    bf16* G     = (bf16*)(ws + OFF_G);
    bf16* MM    = (bf16*)(ws + OFF_M);
    bf16* WSS   = (bf16*)(ws + OFF_WSS);
    bf16* WQKV  = (bf16*)(ws + OFF_WQKV);
    bf16* WPROJ = (bf16*)(ws + OFF_WPROJ);
    bf16* WINV  = (bf16*)(ws + OFF_WINV);
    bf16* WPW   = (bf16*)(ws + OFF_WPW);

    cvt_bf16<<<2916, 256, 0, stream>>>(ss_w, WSS, C6 * C6 / 4);
    cvt_bf16<<<3888, 256, 0, stream>>>(qkv_w, WQKV, 3456 * DD / 4);
    cvt_bf16<<<1296, 256, 0, stream>>>(proj_w, WPROJ, DD * DD / 4);
    cvt_bf16<<<10368, 256, 0, stream>>>(inv_w, WINV, HF2 * DD / 4);
    cvt_bf16<<<5184, 256, 0, stream>>>(pw_w, WPW, DD * HF / 4);

    // LN1 stats: per-block partials (PART1 overlays A1; consumed before prep_cond)
    ln_stats<<<1152, 256, 0, stream>>>(x, PART1);
    reduce_part<<<4, 256, 0, stream>>>(PART1, sums, 288, 0);
    prep_cond<<<dim3(64, 27, 4), 256, 0, stream>>>(cond, A1);
    // ss = silu(cond) @ ss_w^T + ss_b, out [o][16384]
    gemm_bt<0, 1><<<dim3(128, 14), 256, 0, stream>>>(WSS, A1, ss_b, SS, C6, 16384, C6, 0);
    build_tok<<<RTOT, 256, 0, stream>>>(x, gtok, ttok, SS, sums, T);
    // qkv, relu on first 2304 output channels
    gemm_bt<1, 0><<<dim3(33, 27), 256, 0, stream>>>(WQKV, T, nullptr, QKV, 3456, RTOT, DD, 2304);
    hipMemsetAsync(ws + OFF_VK, 0, (size_t)144 * 1056 * 4, stream);
    attn_vk<<<576, 256, 0, stream>>>(QKV, VK);
    attn_out<<<dim3(17, 144), 256, 0, stream>>>(QKV, VK, ATT);
    // proj
    gemm_bt<0, 1><<<dim3(33, 9), 256, 0, stream>>>(WPROJ, ATT, proj_b, APROJ, DD, RTOT, DD, 0);
    // x1 + LN2 partials (PART2 overlays dead QKV region)
    add_attn<<<18432, 256, 0, stream>>>(x, APROJ, SS, out, PART2);
    reduce_part<<<4, 256, 0, stream>>>(PART2, sums, 4608, 8);
    build_tok2<<<4096, 256, 0, stream>>>(out, SS, sums, T2);
    // MLP expand + silu, out [r][9216]
    gemm_bt<2, 2><<<dim3(72, 32), 256, 0, stream>>>(T2, WINV, inv_b, Y, 4096, HF2, DD, 0);
    dwglu<<<dim3(72, 16, 4), 256, 0, stream>>>(Y, dw_w, dw_b, G);
    // MLP project, out [o][4096]
    gemm_bt<0, 0><<<dim3(32, 9), 256, 0, stream>>>(WPW, G, nullptr, MM, DD, 4096, HF, 0);
    add_mlp<<<18432, 256, 0, stream>>>(MM, SS, out);
}

// Round 5
// 1073.585 us; speedup vs baseline: 1.0782x; 1.0598x over previous
//
#include <hip/hip_runtime.h>
#include <hip/hip_bf16.h>
#include <cstdint>

// ---------------------------------------------------------------------------
// SANA MS-AdaLN block on MI355X.
// R1: LN stats via per-block partials (atomic serialization fix).
// R3: 128x256 tile regressed (occupancy). Reverted to 128x128.
// R4 post-mortem: SQ_LDS_BANK_CONFLICT = 8.0 per global_load_lds instruction
//   (structural 1KB-DMA LDS-fill cycles), NOT ds_read conflicts. Dead end.
// R5a: GROUP_M=8 grid swizzle in gemm_bt -> B n-tiles reused 8x back-to-back
//   from L2 instead of L3 re-fetch per m-row (shorter vmcnt drain).
// R5b: build_tok/build_tok2 rewritten as coalesced LDS-transpose kernels
//   (was: stride-4096 gather, ~8-16x over-fetch).
// ---------------------------------------------------------------------------

typedef __bf16 bf16;
typedef bf16 bf16x8 __attribute__((ext_vector_type(8)));
typedef bf16 bf16x4 __attribute__((ext_vector_type(4)));
typedef float f32x4 __attribute__((ext_vector_type(4)));

typedef const __attribute__((address_space(1))) void gas_void;
typedef __attribute__((address_space(3))) void las_void;

__device__ __forceinline__ void gload16(const bf16* g, bf16* l) {
    __builtin_amdgcn_global_load_lds((gas_void*)g, (las_void*)l, 16, 0, 0);
}

// ---- problem constants ----
#define BB 4
#define CC 288
#define HW 4096          // 64*64
#define C6 1728
#define DD 1152
#define SEQ 1026
#define RTOT 4104        // 4*1026
#define NTOK 1024
#define HF 4608
#define HF2 9216
#define NPB 1179648      // elements per batch sample (288*4096)

// ---- workspace layout (bytes) ----
static constexpr size_t OFF_SUMS = 0;                                   // 16 floats
static constexpr size_t OFF_SS   = 256;                                 // bf16 [1728][16384]
static constexpr size_t SS_BYTES = (size_t)C6 * 16384 * 2;              // 56,623,104
static constexpr size_t OFF_R2   = OFF_SS + SS_BYTES;
// phase A
static constexpr size_t OFF_PART1= OFF_R2;                              // f32 [1152][2] (dead before prep_cond)
static constexpr size_t OFF_A1   = OFF_R2;                              // bf16 [16384][1728]
// phase B (A1 dead after GEMM1)
static constexpr size_t OFF_T    = OFF_R2;                              // bf16 [4104][1152]
static constexpr size_t OFF_QKV  = OFF_T   + (size_t)RTOT*DD*2;         // bf16 [3456][4104]
static constexpr size_t OFF_PART2= OFF_QKV;                             // f32 [18432][2] (QKV dead at add_attn)
static constexpr size_t OFF_VK   = OFF_QKV + (size_t)3456*RTOT*2;       // f32  [144][1056]
static constexpr size_t OFF_ATT  = OFF_VK  + (size_t)144*1056*4;        // bf16 [4104][1152]
static constexpr size_t OFF_APROJ= OFF_ATT + (size_t)RTOT*DD*2;         // bf16 [1152][4104]
// phase C (phase B dead after add_attn)
static constexpr size_t OFF_T2   = OFF_R2;                              // bf16 [4096][1152]
static constexpr size_t OFF_Y    = OFF_T2  + (size_t)4096*DD*2;         // bf16 [4096][9216]
static constexpr size_t OFF_G    = OFF_Y   + (size_t)4096*HF2*2;        // bf16 [4096][4608]
static constexpr size_t OFF_M    = OFF_G   + (size_t)4096*HF*2;         // bf16 [1152][4096]
// converted weights (persistent)
static constexpr size_t OFF_W    = OFF_R2  + 132120576;                 // end of phase C
static constexpr size_t OFF_WSS  = OFF_W;
static constexpr size_t OFF_WQKV = OFF_WSS  + (size_t)C6*C6*2;
static constexpr size_t OFF_WPROJ= OFF_WQKV + (size_t)3456*DD*2;
static constexpr size_t OFF_WINV = OFF_WPROJ+ (size_t)DD*DD*2;
static constexpr size_t OFF_WPW  = OFF_WINV + (size_t)HF2*DD*2;

// ---------------------------------------------------------------------------
// fp32 -> bf16 weight conversion
__global__ __launch_bounds__(256) void cvt_bf16(const float* __restrict__ s,
                                                bf16* __restrict__ d, int n4) {
    int i = blockIdx.x * 256 + threadIdx.x;
    if (i < n4) {
        float4 v = ((const float4*)s)[i];
        bf16x4 o = {(bf16)v.x, (bf16)v.y, (bf16)v.z, (bf16)v.w};
        ((bf16x4*)d)[i] = o;
    }
}

// ---------------------------------------------------------------------------
// block reduce (sum, sumsq); thread 0 stores 2 floats (no atomics)
__device__ __forceinline__ void block_reduce2_store(float s1, float s2, float* dst) {
    #pragma unroll
    for (int o = 32; o > 0; o >>= 1) { s1 += __shfl_down(s1, o); s2 += __shfl_down(s2, o); }
    __shared__ float r1[4], r2[4];
    int wave = threadIdx.x >> 6, lane = threadIdx.x & 63;
    if (lane == 0) { r1[wave] = s1; r2[wave] = s2; }
    __syncthreads();
    if (threadIdx.x == 0) {
        dst[0] = r1[0] + r1[1] + r1[2] + r1[3];
        dst[1] = r2[0] + r2[1] + r2[2] + r2[3];
    }
}

// LN1 stats over x: grid 4*288 blocks, 4096 elems/block -> partials
__global__ __launch_bounds__(256) void ln_stats(const float* __restrict__ x, float* __restrict__ part) {
    const float* base = x + (size_t)blockIdx.x * 4096;
    float s1 = 0.f, s2 = 0.f;
    #pragma unroll
    for (int it = 0; it < 4; it++) {
        float4 v = ((const float4*)base)[it * 256 + threadIdx.x];
        s1 += v.x + v.y + v.z + v.w;
        s2 += v.x * v.x + v.y * v.y + v.z * v.z + v.w * v.w;
    }
    block_reduce2_store(s1, s2, part + (size_t)blockIdx.x * 2);
}

// collapse per-block partials -> sums[out_off + b*2 .. +1]. grid = 4 (one per batch)
__global__ __launch_bounds__(256) void reduce_part(const float* __restrict__ part, float* __restrict__ sums,
                                                   int nper, int out_off) {
    int b = blockIdx.x;
    float s1 = 0.f, s2 = 0.f;
    for (int i = threadIdx.x; i < nper; i += 256) {
        s1 += part[(size_t)(b * nper + i) * 2];
        s2 += part[(size_t)(b * nper + i) * 2 + 1];
    }
    block_reduce2_store(s1, s2, sums + out_off + b * 2);
}

// ---------------------------------------------------------------------------
// silu(cond) transpose: (b, k, hw) f32 -> A1[(b,hw)][k] bf16. grid (64,27,4)
__global__ __launch_bounds__(256) void prep_cond(const float* __restrict__ cond, bf16* __restrict__ A1) {
    __shared__ float tile[64][65];
    int b = blockIdx.z, k0 = blockIdx.y * 64, h0 = blockIdx.x * 64;
    int col = threadIdx.x & 63, r4 = threadIdx.x >> 6;
    const float* src = cond + ((size_t)b * C6 + k0) * HW + h0;
    #pragma unroll
    for (int p = 0; p < 16; p++) {
        int kk = r4 + p * 4;
        float v = src[(size_t)kk * HW + col];
        tile[col][kk] = v / (1.f + __expf(-v));
    }
    __syncthreads();
    bf16* dst = A1 + ((size_t)(b * HW + h0)) * C6 + k0;
    #pragma unroll
    for (int p = 0; p < 16; p++) {
        int rr = r4 + p * 4;
        dst[(size_t)rr * C6 + col] = (bf16)tile[rr][col];
    }
}

// ---------------------------------------------------------------------------
// gemm_bt: C[m][n] = sum_k A[m][k]*B[n][k]  (both operands k-contiguous bf16)
// EP: 0=none, 1=relu if m<reluLimit, 2=silu.  BIAS: 0=none, 1=per-m, 2=per-n.
// GROUP_M=8 swizzle: consecutive block ids walk 8 m-tiles per n-tile so the
// B n-tile stays L2-resident across its consumers.
template <int EP, int BIAS>
__global__ __launch_bounds__(256) void gemm_bt(const bf16* __restrict__ A, const bf16* __restrict__ B,
                                               const float* __restrict__ bias, bf16* __restrict__ C,
                                               int M, int N, int K, int reluLimit) {
    __shared__ __align__(16) bf16 As[128 * 32];
    __shared__ __align__(16) bf16 Bs[128 * 32];
    const int tid = threadIdx.x, wave = tid >> 6, lane = tid & 63;

    // ---- GROUP_M grid swizzle (bijection over (gridDim.x, gridDim.y)) ----
    const int nx = gridDim.x, ny = gridDim.y, G = 8;
    int idx = blockIdx.y * nx + blockIdx.x;          // dispatch order (x fastest)
    int band = idx / (G * nx);
    int r = idx - band * (G * nx);
    int gm = min(G, ny - band * G);
    const int m0 = (band * G + r % gm) * 128;
    const int n0 = (r / gm) * 128;

    const int c0 = wave * 128 + lane;          // granule id [0,512)
    const int c1 = c0 + 64;                    // rows +16, same chunk & swizzle
    const int sw = ((c0 >> 2) & 3) ^ ((c0 >> 4) & 3);
    const int ka = (((c0 & 3) ^ sw)) * 8;      // swizzled global chunk (elements)
    int ra0 = min(m0 + (c0 >> 2), M - 1), ra1 = min(m0 + (c1 >> 2), M - 1);
    int rb0 = min(n0 + (c0 >> 2), N - 1), rb1 = min(n0 + (c1 >> 2), N - 1);
    const bf16* gA0 = A + (size_t)ra0 * K + ka;
    const bf16* gA1 = A + (size_t)ra1 * K + ka;
    const bf16* gB0 = B + (size_t)rb0 * K + ka;
    const bf16* gB1 = B + (size_t)rb1 * K + ka;
    bf16* lA0 = As + wave * 1024;
    bf16* lA1 = As + wave * 1024 + 512;
    bf16* lB0 = Bs + wave * 1024;
    bf16* lB1 = Bs + wave * 1024 + 512;

    const int wm = (wave >> 1) * 64, wn = (wave & 1) * 64;
    const int l15 = lane & 15;
    const int sr = (l15 & 3) ^ ((l15 >> 2) & 3);           // s(row) for frag rows
    const int fc = ((lane >> 4) ^ sr) * 8;                 // swizzled chunk offset
    const bf16* fa = As + (wm + l15) * 32 + fc;
    const bf16* fb = Bs + (wn + l15) * 32 + fc;

    f32x4 acc[4][4];
    #pragma unroll
    for (int i = 0; i < 4; i++)
        #pragma unroll
        for (int j = 0; j < 4; j++) acc[i][j] = (f32x4){0.f, 0.f, 0.f, 0.f};

    for (int kt = 0; kt < K; kt += 32) {
        __syncthreads();
        gload16(gA0, lA0); gload16(gA1, lA1);
        gload16(gB0, lB0); gload16(gB1, lB1);
        gA0 += 32; gA1 += 32; gB0 += 32; gB1 += 32;
        __syncthreads();
        bf16x8 af[4], bv[4];
        #pragma unroll
        for (int i = 0; i < 4; i++) af[i] = *(const bf16x8*)(fa + i * 16 * 32);
        #pragma unroll
        for (int j = 0; j < 4; j++) bv[j] = *(const bf16x8*)(fb + j * 16 * 32);
        #pragma unroll
        for (int i = 0; i < 4; i++)
            #pragma unroll
            for (int j = 0; j < 4; j++)
                acc[i][j] = __builtin_amdgcn_mfma_f32_16x16x32_bf16(af[i], bv[j], acc[i][j], 0, 0, 0);
    }

    const int mq = (lane >> 4) * 4, nl = lane & 15;
    #pragma unroll
    for (int i = 0; i < 4; i++) {
        #pragma unroll
        for (int j = 0; j < 4; j++) {
            int n = n0 + wn + j * 16 + nl;
            if (n < N) {
                #pragma unroll
                for (int r2 = 0; r2 < 4; r2++) {
                    int m = m0 + wm + i * 16 + mq + r2;
                    if (m < M) {
                        float v = acc[i][j][r2];
                        if (BIAS == 1) v += bias[m];
                        else if (BIAS == 2) v += bias[n];
                        if (EP == 1) { if (m < reluLimit) v = fmaxf(v, 0.f); }
                        else if (EP == 2) { v = v / (1.f + __expf(-v)); }
                        C[(size_t)m * N + n] = (bf16)v;
                    }
                }
            }
        }
    }
}

// ---------------------------------------------------------------------------
// token build (coalesced): grid (9 cchunk, 32 n1, 4 b), block 256.
// Reads x [b, c0..c0+31, rows 2n1..2n1+1, all w] and sh/sc maps coalesced
// along w; LDS transpose (pad 132) -> writes 32 token rows x 128 contiguous d.
__global__ __launch_bounds__(256) void build_tok_t(const float* __restrict__ xs, const bf16* __restrict__ ss,
                                                   const float* __restrict__ sums, int soff, int shb, int scb,
                                                   bf16* __restrict__ dst, int tokoff, int seqstride) {
    __shared__ bf16 tl[32][132];
    int cch = blockIdx.x, n1 = blockIdx.y, b = blockIdx.z;
    int c0 = cch * 32;
    int tid = threadIdx.x, cl = tid >> 3, wseg = tid & 7;

    float mu = sums[soff + b * 2] * (1.f / (float)NPB);
    float var = sums[soff + b * 2 + 1] * (1.f / (float)NPB) - mu * mu;
    float rsig = rsqrtf(var + 1e-6f);

    int c = c0 + cl;
    #pragma unroll
    for (int hh = 0; hh < 2; hh++) {
        int hw = (2 * n1 + hh) * 64 + wseg * 8;
        const float* xp = xs + ((size_t)b * CC + c) * HW + hw;
        float4 x0 = ((const float4*)xp)[0];
        float4 x1 = ((const float4*)xp)[1];
        bf16x8 scv = *(const bf16x8*)(ss + (size_t)(scb + c) * 16384 + b * HW + hw);
        bf16x8 shv = *(const bf16x8*)(ss + (size_t)(shb + c) * 16384 + b * HW + hw);
        float xv[8] = {x0.x, x0.y, x0.z, x0.w, x1.x, x1.y, x1.z, x1.w};
        #pragma unroll
        for (int k = 0; k < 8; k++) {
            int w = wseg * 8 + k;
            float v = (xv[k] - mu) * rsig * (1.f + (float)scv[k]) + (float)shv[k];
            tl[w >> 1][cl * 4 + hh * 2 + (w & 1)] = (bf16)v;
        }
    }
    __syncthreads();
    int token = tid >> 3, seg = (tid & 7) * 16;
    bf16* drow = dst + ((size_t)(b * seqstride + tokoff + n1 * 32 + token)) * DD + c0 * 4 + seg;
    *(bf16x8*)drow = *(const bf16x8*)&tl[token][seg];
    *(bf16x8*)(drow + 8) = *(const bf16x8*)&tl[token][seg + 8];
}

// global/time token rows: grid (2,4), 256 threads
__global__ __launch_bounds__(256) void copy_gt(const float* __restrict__ gtok, const float* __restrict__ ttok,
                                               bf16* __restrict__ T) {
    int which = blockIdx.x, b = blockIdx.y;
    const float* src = (which == 0 ? gtok : ttok) + b * DD;
    bf16* dst = T + (size_t)(b * SEQ + which) * DD;
    for (int d = threadIdx.x; d < DD; d += 256) dst[d] = (bf16)src[d];
}

// ---------------------------------------------------------------------------
// attention: vk[e][d] = sum_s vpad[s,e]*k[s,d]; grid 144*4 (s-split, atomics)
__global__ __launch_bounds__(256) void attn_vk(const bf16* __restrict__ qkv, float* __restrict__ vk) {
    int bh = blockIdx.x >> 2, sb = blockIdx.x & 3;
    int b = bh / 36, h = bh % 36;
    int s_begin = sb * 288;
    int s_end = min(s_begin + 288, SEQ);
    const bf16* kbase = qkv + (size_t)(DD + h * 32) * RTOT + b * SEQ;
    const bf16* vbase = qkv + (size_t)(2 * DD + h * 32) * RTOT + b * SEQ;
    __shared__ __align__(16) bf16 kk[32][80];
    __shared__ __align__(16) bf16 vv[32][80];
    int tid = threadIdx.x;
    int e = tid >> 3, dg = (tid & 7) * 4;
    int lrow = tid >> 3, lcol = (tid & 7) * 8;
    float a0 = 0.f, a1 = 0.f, a2 = 0.f, a3 = 0.f, aD = 0.f;
    for (int s0 = s_begin; s0 < s_end; s0 += 64) {
        __syncthreads();
        #pragma unroll
        for (int j = 0; j < 8; j++) {
            int s = s0 + lcol + j;
            bool ok = s < s_end;
            kk[lrow][lcol + j] = ok ? kbase[(size_t)lrow * RTOT + s] : (bf16)0.f;
            vv[lrow][lcol + j] = ok ? vbase[(size_t)lrow * RTOT + s] : (bf16)0.f;
        }
        __syncthreads();
        #pragma unroll
        for (int j0 = 0; j0 < 64; j0 += 8) {
            bf16x8 vvv = *(const bf16x8*)&vv[e][j0];
            bf16x8 k0 = *(const bf16x8*)&kk[dg + 0][j0];
            bf16x8 k1 = *(const bf16x8*)&kk[dg + 1][j0];
            bf16x8 k2 = *(const bf16x8*)&kk[dg + 2][j0];
            bf16x8 k3 = *(const bf16x8*)&kk[dg + 3][j0];
            #pragma unroll
            for (int j = 0; j < 8; j++) {
                float vf = (float)vvv[j];
                a0 += vf * (float)k0[j];
                a1 += vf * (float)k1[j];
                a2 += vf * (float)k2[j];
                a3 += vf * (float)k3[j];
            }
            if (tid < 32) {
                bf16x8 kd = *(const bf16x8*)&kk[tid][j0];
                #pragma unroll
                for (int j = 0; j < 8; j++) aD += (float)kd[j];
            }
        }
    }
    float* dst = vk + (size_t)bh * 1056;
    atomicAdd(&dst[e * 32 + dg + 0], a0);
    atomicAdd(&dst[e * 32 + dg + 1], a1);
    atomicAdd(&dst[e * 32 + dg + 2], a2);
    atomicAdd(&dst[e * 32 + dg + 3], a3);
    if (tid < 32) atomicAdd(&dst[1024 + tid], aD);
}

// attention normalize: out[s][e] = (sum_d vk[e][d] q[s][d]) / (den + eps)
__global__ __launch_bounds__(256) void attn_out(const bf16* __restrict__ qkv, const float* __restrict__ vk,
                                                bf16* __restrict__ att) {
    int bh = blockIdx.y, b = bh / 36, h = bh % 36;
    int s0 = blockIdx.x * 64;
    __shared__ float vks[1056];
    __shared__ __align__(16) bf16 qs[32][80];
    int tid = threadIdx.x;
    for (int i = tid; i < 1056; i += 256) vks[i] = vk[(size_t)bh * 1056 + i];
    const bf16* qbase = qkv + (size_t)(h * 32) * RTOT + b * SEQ;
    int lrow = tid >> 3, lcol = (tid & 7) * 8;
    #pragma unroll
    for (int j = 0; j < 8; j++) {
        int s = s0 + lcol + j;
        qs[lrow][lcol + j] = (s < SEQ) ? qbase[(size_t)lrow * RTOT + s] : (bf16)0.f;
    }
    __syncthreads();
    int sl = tid >> 2, eg = (tid & 3) * 8;
    int s = s0 + sl;
    float num[8] = {0.f, 0.f, 0.f, 0.f, 0.f, 0.f, 0.f, 0.f};
    float den = 0.f;
    #pragma unroll
    for (int d = 0; d < 32; d++) {
        float qv = (float)qs[d][sl];
        den += vks[1024 + d] * qv;
        #pragma unroll
        for (int t = 0; t < 8; t++) num[t] += vks[(eg + t) * 32 + d] * qv;
    }
    if (s < SEQ) {
        float inv = 1.f / (den + 1e-8f);
        bf16* dst = att + ((size_t)(b * SEQ + s)) * DD + h * 32 + eg;
        #pragma unroll
        for (int t = 0; t < 8; t++) dst[t] = (bf16)(num[t] * inv);
    }
}

// ---------------------------------------------------------------------------
// x1 = x + comb(aproj)*g_msa -> d_out (fp32), LN2 partials (no atomics)
__global__ __launch_bounds__(256) void add_attn(const float* __restrict__ x, const bf16* __restrict__ aproj,
                                                const bf16* __restrict__ ss, float* __restrict__ xo,
                                                float* __restrict__ part) {
    int b = blockIdx.x / 4608;
    size_t idx = (size_t)blockIdx.x * 256 + threadIdx.x;
    size_t local = idx - (size_t)b * NPB;
    int c = (int)(local >> 12), hw = (int)(local & 4095);
    int hh = hw >> 6, w = hw & 63;
    int n = (hh >> 1) * 32 + (w >> 1);
    int dd = c * 4 + (hh & 1) * 2 + (w & 1);
    float a = (float)aproj[(size_t)dd * RTOT + b * SEQ + 2 + n];
    float g = (float)ss[(size_t)(576 + c) * 16384 + b * HW + hw];
    float v = x[idx] + a * g;
    xo[idx] = v;
    block_reduce2_store(v, v * v, part + (size_t)blockIdx.x * 2);
}

// ---------------------------------------------------------------------------
// depthwise 3x3 + bias + GLU. grid (72 cchunk, 16 tile, 4 b), block 256.
__global__ __launch_bounds__(256) void dwglu(const bf16* __restrict__ y, const float* __restrict__ dw_w,
                                             const float* __restrict__ dw_b, bf16* __restrict__ g) {
    __shared__ __align__(16) bf16 xs[6400];
    __shared__ __align__(16) bf16 gs[6400];
    int b = blockIdx.z, tile = blockIdx.y, c0 = blockIdx.x * 64;
    int ty = (tile >> 2) * 8, tx = (tile & 3) * 8;
    int tid = threadIdx.x, cc = tid & 63, pg = tid >> 6;
    for (int p = pg; p < 100; p += 4) {
        int py = ty + p / 10 - 1, px = tx + p % 10 - 1;
        bool in = (py >= 0 && py < 32 && px >= 0 && px < 32);
        size_t base = ((size_t)(b * NTOK + py * 32 + px)) * HF2;
        xs[p * 64 + cc] = in ? y[base + c0 + cc] : (bf16)0.f;
        gs[p * 64 + cc] = in ? y[base + HF + c0 + cc] : (bf16)0.f;
    }
    float wx[9], wg[9];
    #pragma unroll
    for (int t = 0; t < 9; t++) {
        wx[t] = dw_w[(size_t)(c0 + cc) * 9 + t];
        wg[t] = dw_w[(size_t)(HF + c0 + cc) * 9 + t];
    }
    float bx = dw_b[c0 + cc], bg = dw_b[HF + c0 + cc];
    __syncthreads();
    for (int p = pg * 16; p < pg * 16 + 16; p++) {
        int py = p >> 3, px = p & 7;
        float ax = bx, ag = bg;
        #pragma unroll
        for (int dy = 0; dy < 3; dy++)
            #pragma unroll
            for (int dx = 0; dx < 3; dx++) {
                int q = (py + dy) * 10 + (px + dx);
                ax += (float)xs[q * 64 + cc] * wx[dy * 3 + dx];
                ag += (float)gs[q * 64 + cc] * wg[dy * 3 + dx];
            }
        float out = ax * (ag / (1.f + __expf(-ag)));
        g[((size_t)(b * NTOK + (ty + py) * 32 + tx + px)) * HF + c0 + cc] = (bf16)out;
    }
}

// final: out = x1 + comb(m)*g_mlp
__global__ __launch_bounds__(256) void add_mlp(const bf16* __restrict__ mm, const bf16* __restrict__ ss,
                                               float* __restrict__ xo) {
    int b = blockIdx.x / 4608;
    size_t idx = (size_t)blockIdx.x * 256 + threadIdx.x;
    size_t local = idx - (size_t)b * NPB;
    int c = (int)(local >> 12), hw = (int)(local & 4095);
    int hh = hw >> 6, w = hw & 63;
    int n = (hh >> 1) * 32 + (w >> 1);
    int dd = c * 4 + (hh & 1) * 2 + (w & 1);
    float mv = (float)mm[(size_t)dd * 4096 + b * NTOK + n];
    float g = (float)ss[(size_t)(1440 + c) * 16384 + b * HW + hw];
    xo[idx] = xo[idx] + mv * g;
}

// ---------------------------------------------------------------------------
extern "C" void kernel_launch(void* const* d_in, const int* in_sizes, int n_in,
                              void* d_out, int out_size, void* d_ws, size_t ws_size,
                              hipStream_t stream) {
    (void)in_sizes; (void)n_in; (void)out_size; (void)ws_size;
    const float* x      = (const float*)d_in[0];
    const float* cond   = (const float*)d_in[1];
    const float* gtok   = (const float*)d_in[2];
    const float* ttok   = (const float*)d_in[3];
    const float* ss_w   = (const float*)d_in[4];
    const float* ss_b   = (const float*)d_in[5];
    const float* qkv_w  = (const float*)d_in[6];
    const float* proj_w = (const float*)d_in[7];
    const float* proj_b = (const float*)d_in[8];
    const float* inv_w  = (const float*)d_in[9];
    const float* inv_b  = (const float*)d_in[10];
    const float* dw_w   = (const float*)d_in[11];
    const float* dw_b   = (const float*)d_in[12];
    const float* pw_w   = (const float*)d_in[13];
    float* out = (float*)d_out;
    char* ws = (char*)d_ws;

    float* sums  = (float*)(ws + OFF_SUMS);
    float* PART1 = (float*)(ws + OFF_PART1);
    float* PART2 = (float*)(ws + OFF_PART2);
    bf16* SS    = (bf16*)(ws + OFF_SS);
    bf16* A1    = (bf16*)(ws + OFF_A1);
    bf16* T     = (bf16*)(ws + OFF_T);
    bf16* QKV   = (bf16*)(ws + OFF_QKV);
    float* VK   = (float*)(ws + OFF_VK);
    bf16* ATT   = (bf16*)(ws + OFF_ATT);
    bf16* APROJ = (bf16*)(ws + OFF_APROJ);
    bf16* T2    = (bf16*)(ws + OFF_T2);
    bf16* Y     = (bf16*)(ws + OFF_Y);
    bf16* G     = (bf16*)(ws + OFF_G);
    bf16* MM    = (bf16*)(ws + OFF_M);
    bf16* WSS   = (bf16*)(ws + OFF_WSS);
    bf16* WQKV  = (bf16*)(ws + OFF_WQKV);
    bf16* WPROJ = (bf16*)(ws + OFF_WPROJ);
    bf16* WINV  = (bf16*)(ws + OFF_WINV);
    bf16* WPW   = (bf16*)(ws + OFF_WPW);

    cvt_bf16<<<2916, 256, 0, stream>>>(ss_w, WSS, C6 * C6 / 4);
    cvt_bf16<<<3888, 256, 0, stream>>>(qkv_w, WQKV, 3456 * DD / 4);
    cvt_bf16<<<1296, 256, 0, stream>>>(proj_w, WPROJ, DD * DD / 4);
    cvt_bf16<<<10368, 256, 0, stream>>>(inv_w, WINV, HF2 * DD / 4);
    cvt_bf16<<<5184, 256, 0, stream>>>(pw_w, WPW, DD * HF / 4);

    // LN1 stats: per-block partials (PART1 overlays A1; consumed before prep_cond)
    ln_stats<<<1152, 256, 0, stream>>>(x, PART1);
    reduce_part<<<4, 256, 0, stream>>>(PART1, sums, 288, 0);
    prep_cond<<<dim3(64, 27, 4), 256, 0, stream>>>(cond, A1);
    // ss = silu(cond) @ ss_w^T + ss_b, out [o][16384]
    gemm_bt<0, 1><<<dim3(128, 14), 256, 0, stream>>>(WSS, A1, ss_b, SS, C6, 16384, C6, 0);
    build_tok_t<<<dim3(9, 32, 4), 256, 0, stream>>>(x, SS, sums, 0, 0, 288, T, 2, SEQ);
    copy_gt<<<dim3(2, 4), 256, 0, stream>>>(gtok, ttok, T);
    // qkv, relu on first 2304 output channels
    gemm_bt<1, 0><<<dim3(33, 27), 256, 0, stream>>>(WQKV, T, nullptr, QKV, 3456, RTOT, DD, 2304);
    hipMemsetAsync(ws + OFF_VK, 0, (size_t)144 * 1056 * 4, stream);
    attn_vk<<<576, 256, 0, stream>>>(QKV, VK);
    attn_out<<<dim3(17, 144), 256, 0, stream>>>(QKV, VK, ATT);
    // proj
    gemm_bt<0, 1><<<dim3(33, 9), 256, 0, stream>>>(WPROJ, ATT, proj_b, APROJ, DD, RTOT, DD, 0);
    // x1 + LN2 partials (PART2 overlays dead QKV region)
    add_attn<<<18432, 256, 0, stream>>>(x, APROJ, SS, out, PART2);
    reduce_part<<<4, 256, 0, stream>>>(PART2, sums, 4608, 8);
    build_tok_t<<<dim3(9, 32, 4), 256, 0, stream>>>(out, SS, sums, 8, 864, 1152, T2, 0, 1024);
    // MLP expand + silu, out [r][9216]
    gemm_bt<2, 2><<<dim3(72, 32), 256, 0, stream>>>(T2, WINV, inv_b, Y, 4096, HF2, DD, 0);
    dwglu<<<dim3(72, 16, 4), 256, 0, stream>>>(Y, dw_w, dw_b, G);
    // MLP project, out [o][4096]
    gemm_bt<0, 0><<<dim3(32, 9), 256, 0, stream>>>(WPW, G, nullptr, MM, DD, 4096, HF, 0);
    add_mlp<<<18432, 256, 0, stream>>>(MM, SS, out);
}